// Round 11
// baseline (174.619 us; speedup 1.0000x reference)
//
#include <hip/hip_runtime.h>
#include <math.h>

// Problem constants (from reference): N=100000, S=64, Q=50, P=3
#define N_Q 50
#define N_P 3
#define N_S 64
#define ROW 150        // Q*P floats per pauli word
#define THREADS 512    // 8 waves: 0..3 scatter-group, 4..7 LDS-group
#define GRID 256       // exactly 1 block per CU; balanced row partition
#define SCHUNK 16      // every wave covers 16 s-values (4 waves = all 64 s)
#define L_ROWS 128     // LDS-staged rows per block (slots 0..127), 2 per lane
#define S_SLOTS 5      // scattered slots per lane (slots 128..447)
#define SLOTS 448      // 64*(2+5) row-slots per block >= max rows/block (391)
#define ASTRIDE 151    // LDS A-tile stride: coprime 32 -> b32 reads conflict-free
#define NF2 75         // float2 per A row

// ws layout (bytes): [0..2048) partials double[256]; [3200..3204) cnt
#define WS_CNT_OFF 3200

__device__ __forceinline__ float softplus20(float x) {
    float z = x * 20.0f;
    return fmaxf(z, 0.0f) + log1pf(expf(-fabsf(z)));  // stable softplus
}

// R rows x 16 s (4 groups of 4) for one q. Hq is wave-uniform LDS ->
// conflict-free b128 broadcast. Per-(s,q,row) math order EXACTLY matches
// every verified round: t = fmaf(h0,a0,fmaf(h1,a1,h2*a2)); prod *= t.
template <int R>
__device__ __forceinline__ void computeQR(const float4* __restrict__ Hq,
                                          const float (&a)[R][3],
                                          float (&p)[R][SCHUNK]) {
    #pragma unroll
    for (int g = 0; g < 4; ++g) {
        float4 b0 = Hq[3 * g], b1 = Hq[3 * g + 1], b2 = Hq[3 * g + 2];
        // layout per 4 s: [h00 h01 h02 h10][h11 h12 h20 h21][h22 h30 h31 h32]
        #pragma unroll
        for (int r = 0; r < R; ++r) {
            p[r][4*g+0] *= fmaf(b0.x, a[r][0], fmaf(b0.y, a[r][1], b0.z * a[r][2]));
            p[r][4*g+1] *= fmaf(b0.w, a[r][0], fmaf(b1.x, a[r][1], b1.y * a[r][2]));
            p[r][4*g+2] *= fmaf(b1.z, a[r][0], fmaf(b1.w, a[r][1], b2.x * a[r][2]));
            p[r][4*g+3] *= fmaf(b2.y, a[r][0], fmaf(b2.z, a[r][1], b2.w * a[r][2]));
        }
    }
}

__global__ __launch_bounds__(THREADS, 2) void main_kernel(
    const float* __restrict__ A, const float* __restrict__ coeff,
    const float* __restrict__ heads_param, const float* __restrict__ hr_param,
    double* __restrict__ partials, int* __restrict__ cnt,
    float* __restrict__ out, int N) {
    __shared__ float hHs[N_Q * N_S * 3];      // 38400 B, q-major normalized H
    __shared__ float Atile[L_ROWS * ASTRIDE]; // 77312 B staged A rows
    __shared__ float hrvl[N_S];
    __shared__ float covs[4][SLOTS];          // 7168 B: [s-chunk][slot]
    __shared__ double redd[8];
    __shared__ double redf[8];
    __shared__ int isLast;

    const int tid = threadIdx.x;
    const int lane = tid & 63;
    const int wave = tid >> 6;
    const int b = blockIdx.x;

    // balanced contiguous row partition: every block gets 390 or 391 rows
    const int q0 = N / GRID, r0 = N % GRID;
    const int base = b * q0 + (b < r0 ? b : r0);
    const int count = q0 + (b < r0 ? 1 : 0);
    const int cmax = (count > 0 ? count : 1) - 1;   // last valid local row

    // --- fused precompute: hrv (wave 0, r0-verified math) ---
    if (tid < N_S) {
        float sp = softplus20(hr_param[tid]);
        float tot = sp;
        #pragma unroll
        for (int off = 32; off; off >>= 1) tot += __shfl_xor(tot, off);
        float hr = sp / fmaxf(tot, 1e-12f);
        hrvl[tid] = (hr + 0.001f / (float)N_S) / 1.001f;
    }
    // --- fused precompute: H softplus + L1-normalize straight into LDS.
    // EXACT reference semantics: h_p = sp_p / max(sum, EPS). Writes at
    // q*192 + s*3 (stride-3, gcd(3,32)=1 -> conflict-free). ---
    for (int e = tid; e < N_S * N_Q; e += THREADS) {
        int q = e / N_S;
        int s = e - q * N_S;
        const float* hp = heads_param + ((size_t)s * N_Q + q) * N_P;
        float sp0 = softplus20(hp[0]);
        float sp1 = softplus20(hp[1]);
        float sp2 = softplus20(hp[2]);
        float denom = fmaxf(sp0 + sp1 + sp2, 1e-12f);
        float* o = hHs + (q * N_S + s) * 3;
        o[0] = sp0 / denom;
        o[1] = sp1 / denom;
        o[2] = sp2 / denom;
    }
    // --- stage A rows [base, base+128) into LDS, coalesced float2 ---
    {
        const float2* __restrict__ Ag = (const float2*)A;
        const size_t gb = (size_t)base * NF2;
        for (int g = tid; g < L_ROWS * NF2; g += THREADS) {
            int rr = g / NF2, c = g - rr * NF2;
            int src = rr <= cmax ? rr : cmax;          // no-op at N=100000
            float2 v = Ag[gb + (size_t)src * NF2 + c];
            float* d = Atile + rr * ASTRIDE + 2 * c;
            d[0] = v.x; d[1] = v.y;
        }
    }
    __syncthreads();

    const int sgrp = (wave < 4) ? wave : (wave - 4);   // s-chunk 0..3
    const float4* __restrict__ Hbase = (const float4*)hHs + 12 * sgrp;
    const int s0 = sgrp * SCHUNK;

    if (wave < 4) {
        // ===== scatter group: 5 rows/lane from global (r7-verified pattern) =====
        const float2* __restrict__ pS[S_SLOTS];
        #pragma unroll
        for (int j = 0; j < S_SLOTS; ++j) {
            int slot = L_ROWS + 64 * j + lane;
            int rr = slot <= cmax ? slot : cmax;       // only j=4 ever clamps
            pS[j] = (const float2*)A + ((size_t)base + rr) * NF2;
        }
        float prod[S_SLOTS][SCHUNK];
        #pragma unroll
        for (int j = 0; j < S_SLOTS; ++j)
            #pragma unroll
            for (int i = 0; i < SCHUNK; ++i) prod[j][i] = 1.0f;

        float2 x[S_SLOTS][3];
        #pragma unroll
        for (int j = 0; j < S_SLOTS; ++j) {
            x[j][0] = pS[j][0]; x[j][1] = pS[j][1]; x[j][2] = pS[j][2];
        }
        #pragma unroll 5
        for (int w = 0; w < N_Q / 2; ++w) {
            const int nb = (w < N_Q / 2 - 1) ? 3 * w + 3 : 0;   // clamped
            float2 nx[S_SLOTS][3];
            #pragma unroll
            for (int j = 0; j < S_SLOTS; ++j) {
                nx[j][0] = pS[j][nb]; nx[j][1] = pS[j][nb + 1]; nx[j][2] = pS[j][nb + 2];
            }
            const float4* Hq = Hbase + 96 * w;
            float aq[S_SLOTS][3], cq[S_SLOTS][3];
            #pragma unroll
            for (int j = 0; j < S_SLOTS; ++j) {
                aq[j][0] = x[j][0].x; aq[j][1] = x[j][0].y; aq[j][2] = x[j][1].x;
                cq[j][0] = x[j][1].y; cq[j][1] = x[j][2].x; cq[j][2] = x[j][2].y;
            }
            computeQR<S_SLOTS>(Hq,      aq, prod);      // q = 2w
            computeQR<S_SLOTS>(Hq + 48, cq, prod);      // q = 2w+1
            #pragma unroll
            for (int j = 0; j < S_SLOTS; ++j) {
                x[j][0] = nx[j][0]; x[j][1] = nx[j][1]; x[j][2] = nx[j][2];
            }
        }
        #pragma unroll
        for (int j = 0; j < S_SLOTS; ++j) {
            float acc = 0.0f;
            #pragma unroll
            for (int i = 0; i < SCHUNK; ++i) acc = fmaf(hrvl[s0 + i], prod[j][i], acc);
            covs[sgrp][L_ROWS + 64 * j + lane] = acc;
        }
    } else {
        // ===== LDS group: 2 rows/lane from Atile (r5/r10-verified reads) =====
        const float* __restrict__ Ar0 = Atile + lane * ASTRIDE;
        const float* __restrict__ Ar1 = Atile + (lane + 64) * ASTRIDE;
        float prod[2][SCHUNK];
        #pragma unroll
        for (int j = 0; j < 2; ++j)
            #pragma unroll
            for (int i = 0; i < SCHUNK; ++i) prod[j][i] = 1.0f;

        #pragma unroll 5
        for (int w = 0; w < N_Q / 2; ++w) {
            const int o = 6 * w;
            float aq[2][3] = {{Ar0[o], Ar0[o+1], Ar0[o+2]},
                              {Ar1[o], Ar1[o+1], Ar1[o+2]}};
            float cq[2][3] = {{Ar0[o+3], Ar0[o+4], Ar0[o+5]},
                              {Ar1[o+3], Ar1[o+4], Ar1[o+5]}};
            const float4* Hq = Hbase + 96 * w;
            computeQR<2>(Hq,      aq, prod);            // q = 2w
            computeQR<2>(Hq + 48, cq, prod);            // q = 2w+1
        }
        float acc0 = 0.0f, acc1 = 0.0f;
        #pragma unroll
        for (int i = 0; i < SCHUNK; ++i) {
            acc0 = fmaf(hrvl[s0 + i], prod[0][i], acc0);
            acc1 = fmaf(hrvl[s0 + i], prod[1][i], acc1);
        }
        covs[sgrp][lane]      = acc0;
        covs[sgrp][64 + lane] = acc1;
    }
    __syncthreads();

    // --- finalize: slot = tid; cov = 4 s-chunks summed sequentially (the
    // verified association); term = c^2/cov; invalid slots contribute 0 ---
    double td = 0.0;
    if (tid < SLOTS) {
        const int slot = tid;
        float cov = covs[0][slot] + covs[1][slot] + covs[2][slot] + covs[3][slot];
        if (slot < count) {
            float c = coeff[base + slot];
            td = (double)((c * c) / cov);
        }
    }
    #pragma unroll
    for (int off = 32; off; off >>= 1) td += __shfl_down(td, off);
    if (lane == 0) redd[wave] = td;
    __syncthreads();

    if (tid == 0) {
        double bs = 0.0;
        #pragma unroll
        for (int wv = 0; wv < 8; ++wv) bs += redd[wv];
        partials[b] = bs;
        __threadfence();                 // release partial
        int v = atomicAdd(cnt, 1);
        isLast = (v == (int)gridDim.x - 1);
    }
    __syncthreads();

    if (isLast) {                        // last-finishing block reduces all
        __threadfence();                 // acquire
        double s = 0.0;
        for (int i = tid; i < (int)gridDim.x; i += THREADS) s += partials[i];
        #pragma unroll
        for (int off = 32; off; off >>= 1) s += __shfl_down(s, off);
        if (lane == 0) redf[wave] = s;
        __syncthreads();
        if (tid == 0) {
            double t = 0.0;
            #pragma unroll
            for (int wv = 0; wv < 8; ++wv) t += redf[wv];
            out[0] = (float)t;
        }
    }
}

extern "C" void kernel_launch(void* const* d_in, const int* in_sizes, int n_in,
                              void* d_out, int out_size, void* d_ws, size_t ws_size,
                              hipStream_t stream) {
    const float* A           = (const float*)d_in[0];  // [N, Q, P]
    const float* coeff       = (const float*)d_in[1];  // [N]
    const float* heads_param = (const float*)d_in[2];  // [S, Q, P]
    const float* hr_param    = (const float*)d_in[3];  // [S]
    const int N = in_sizes[1];

    char* ws = (char*)d_ws;
    double* partials = (double*)ws;
    int*   cnt = (int*)(ws + WS_CNT_OFF);
    float* out = (float*)d_out;

    hipMemsetAsync(cnt, 0, sizeof(int), stream);  // ws is re-poisoned per launch
    main_kernel<<<GRID, THREADS, 0, stream>>>(A, coeff, heads_param, hr_param,
                                              partials, cnt, out, N);
}